// Round 6
// baseline (1826.620 us; speedup 1.0000x reference)
//
#include <hip/hip_runtime.h>

#define NB 4
#define NC 3
#define BC 12
#define HW 65536
#define KCAP 32
#define MAXI 5
#define RUNCAP 16384
#define NSLOT 120     // 10 steps x 12 (b,c) slots
#define NCH 24        // chain slots: 2 passes x 12

typedef unsigned long long u64;
typedef unsigned int u32;

// ---------------- union-find (lock-free, link-to-MAX, path halving) ----------------
// root = MAX run index of the component -> root run holds the comp's max pixel.
__device__ __forceinline__ int uf_find(int* P, int x){
  while (true){
    int p = P[x];
    if (p == x) return x;
    int gp = P[p];
    if (gp == p) return p;
    P[x] = gp;   // path halving
    x = gp;
  }
}
__device__ __forceinline__ void uf_union_max(int* P, int a, int b){
  while (true){
    a = uf_find(P, a); b = uf_find(P, b);
    if (a == b) return;
    if (a > b){ int t = a; a = b; b = t; }   // a < b: link smaller root to larger
    int old = atomicCAS(&P[a], a, b);
    if (old == a) return;
    a = old;
  }
}

// walk runs of a 256-bit row (4 u64 words); emit(start, end_exclusive)
template<typename F>
__device__ __forceinline__ void walk_runs(const u64* wv, F&& emit){
  int open_s = -1;
  #pragma unroll
  for (int wi = 0; wi < 4; wi++){
    u64 v = wv[wi];
    int base = wi << 6;
    int pos = 0;
    while (pos < 64){
      u64 rem = v >> pos;
      if (open_s >= 0){
        u64 nz = ~rem;
        int z = nz ? __builtin_ctzll(nz) : 64;     // first zero at/after pos
        if (z >= 64 - pos){ pos = 64; }            // run continues past word
        else { emit(open_s, base + pos + z); open_s = -1; pos += z; }
      } else {
        if (rem == 0ull){ pos = 64; }
        else {
          int o = __builtin_ctzll(rem);            // first one
          open_s = base + pos + o;
          pos += o;
        }
      }
    }
  }
  if (open_s >= 0) emit(open_s, 256);
}

// ---------------- binarization: both base masks (pred -> g=0, tgt -> g=5) ----------------
__global__ void k_bin(const float* __restrict__ pred, const float* __restrict__ gum,
                      const int* __restrict__ tgt, u64* __restrict__ bmAll){
  int g = blockIdx.x * 256 + threadIdx.x;    // NB*HW threads
  int b = g >> 16, p = g & (HW - 1);
  size_t base = (size_t)b * NC * HW + p;
  float v0 = pred[base]        + gum[base];
  float v1 = pred[base + HW]   + gum[base + HW];
  float v2 = pred[base + 2*HW] + gum[base + 2*HW];
  int a = 0; float m = v0;
  if (v1 > m){ m = v1; a = 1; }
  if (v2 > m){ m = v2; a = 2; }
  int tg = tgt[(size_t)b * HW + p];
  u64 p0 = __ballot(a == 0), p1 = __ballot(a == 1), p2 = __ballot(a == 2);
  u64 t0 = __ballot(tg == 0), t1 = __ballot(tg == 1), t2 = __ballot(tg == 2);
  if ((threadIdx.x & 63) == 0){
    int w = p >> 6;
    int sp = b * NC;                       // pass0 base: step g=0
    bmAll[(size_t)(sp + 0) * 1024 + w] = p0;
    bmAll[(size_t)(sp + 1) * 1024 + w] = p1;
    bmAll[(size_t)(sp + 2) * 1024 + w] = p2;
    int st = 60 + b * NC;                  // pass1 base: step g=5
    bmAll[(size_t)(st + 0) * 1024 + w] = t0;
    bmAll[(size_t)(st + 1) * 1024 + w] = t1;
    bmAll[(size_t)(st + 2) * 1024 + w] = t2;
  }
}

// ---------------- 5x5 morphology on bitmaps: 4 independent jobs per launch ----------------
__global__ void k_morph4(const u64* __restrict__ bmAll, u64* __restrict__ bmAllW,
                         int4 srcs, int4 dsts, int4 flgs){
  int t = blockIdx.x * 256 + threadIdx.x;  // 4 * 12 * 1024 = 49152
  int job = t / 12288, rest = t % 12288;
  int s = rest >> 10, word = rest & 1023;
  int row = word >> 2, w = word & 3;
  int srcG = job == 0 ? srcs.x : job == 1 ? srcs.y : job == 2 ? srcs.z : srcs.w;
  int dstG = job == 0 ? dsts.x : job == 1 ? dsts.y : job == 2 ? dsts.z : dsts.w;
  int er   = job == 0 ? flgs.x : job == 1 ? flgs.y : job == 2 ? flgs.z : flgs.w;
  const u64* bs = bmAll + (size_t)(srcG * BC + s) * 1024;
  u64 res = er ? ~0ull : 0ull;
  for (int dy = -2; dy <= 2; dy++){
    int y = row + dy;
    if (y < 0 || y > 255){ if (er) res = 0; continue; }
    const u64* rw = bs + y * 4;
    u64 m = rw[w];
    u64 l = (w > 0) ? rw[w-1] : 0ull;
    u64 r = (w < 3) ? rw[w+1] : 0ull;
    u64 x1l = (m << 1) | (l >> 63);
    u64 x2l = (m << 2) | (l >> 62);
    u64 x1r = (m >> 1) | (r << 63);
    u64 x2r = (m >> 2) | (r << 62);
    u64 h = er ? (m & x1l & x2l & x1r & x2r) : (m | x1l | x2l | x1r | x2r);
    res = er ? (res & h) : (res | h);
  }
  bmAllW[(size_t)(dstG * BC + s) * 1024 + word] = res;
}

// ---------------- run-based CC + aggregation + top-32 selection, one block per slot ----------------
// per-run arrays live in GLOBAL (per-slot slices, L2-resident); LDS holds only small scratch.
__global__ __launch_bounds__(256) void k_cc_runs(
    const u64* __restrict__ bmAll, u32* __restrict__ runPack, int* __restrict__ runPar,
    int* __restrict__ runSz, int* __restrict__ rootIx, int* __restrict__ runCnt,
    float* __restrict__ sSel, float* __restrict__ scaleSel){
  __shared__ int rs[257];
  __shared__ u32 used[RUNCAP/32];          // 2 KB
  __shared__ int selRoot[KCAP];
  __shared__ float rk[256];
  __shared__ int ri[256], re[256];
  __shared__ int stop, nRootS;
  int u = blockIdx.x, t = threadIdx.x;     // thread t = row t
  u64 wv[4];
  const u64* bp = bmAll + (size_t)u * 1024 + t * 4;
  #pragma unroll
  for (int i = 0; i < 4; i++) wv[i] = bp[i];
  int nr = 0;
  walk_runs(wv, [&](int a, int b){ (void)a; (void)b; nr++; });
  rs[t] = nr;
  for (int i = t; i < RUNCAP/32; i += 256) used[i] = 0;
  if (t < KCAP) selRoot[t] = -1;
  if (t == 0){ stop = 0; nRootS = 0; }
  __syncthreads();
  // inclusive Hillis-Steele scan of run counts
  for (int d = 1; d < 256; d <<= 1){
    int add = (t >= d) ? rs[t - d] : 0;
    __syncthreads();
    rs[t] += add;
    __syncthreads();
  }
  int incl = rs[t];
  __syncthreads();
  rs[t] = incl - nr;                 // exclusive offset
  if (t == 255) rs[256] = incl;      // total
  __syncthreads();
  int NR = rs[256];
  int NRc = NR < RUNCAP ? NR : RUNCAP;
  size_t base = (size_t)u * RUNCAP;
  // emit runs to global; init par/sz
  {
    int o = rs[t];
    walk_runs(wv, [&](int a, int b){
      if (o < RUNCAP){
        runPack[base + o] = 0xFF000000u | ((u32)t << 16) | ((u32)a << 8) | (u32)(b - 1);
        runPar[base + o]  = o;
        runSz[base + o]   = 0;
      }
      o++;
    });
  }
  __syncthreads();
  // unions: my runs (row t) vs runs of row t-1 (re-walked from L2), 8-connectivity |dx|<=1
  if (t >= 1 && rs[t] < RUNCAP){
    int aBase = rs[t-1];
    int* P = runPar + base;
    u64 pv[4];
    const u64* pb = bmAll + (size_t)u * 1024 + (t-1) * 4;
    #pragma unroll
    for (int i = 0; i < 4; i++) pv[i] = pb[i];
    int myIdx = rs[t];
    walk_runs(wv, [&](int s2, int e2){
      int E2 = e2 - 1;
      if (myIdx < RUNCAP){
        int oIdx = aBase;
        walk_runs(pv, [&](int s1, int e1){
          int E1 = e1 - 1;
          if (oIdx < RUNCAP && s1 <= E2 + 1 && s2 <= E1 + 1)
            uf_union_max(P, myIdx, oIdx);
          oIdx++;
        });
      }
      myIdx++;
    });
  }
  __syncthreads();
  // flatten
  for (int i = t; i < NRc; i += 256){
    int r = i, p = runPar[base + r];
    while (p != r){ r = p; p = runPar[base + r]; }
    runPar[base + i] = r;
  }
  __syncthreads();
  // aggregate sizes per root; compact roots (label>0); global max fg pixel
  int lm = 0;
  for (int i = t; i < NRc; i += 256){
    u32 v = runPack[base + i];
    int row = (v >> 16) & 255, s0 = (v >> 8) & 255, E = v & 255;
    int r = runPar[base + i];
    atomicAdd(&runSz[base + r], E - s0 + 1);
    int pix = row * 256 + E;
    lm = max(lm, pix);
    if (r == i && pix > 0){                 // root run holds comp's max pixel (= label)
      int pos = atomicAdd(&nRootS, 1);
      rootIx[base + pos] = i;
    }
  }
  rs[t] = lm;
  __syncthreads();
  for (int off = 128; off > 0; off >>= 1){
    if (t < off) rs[t] = max(rs[t], rs[t + off]);
    __syncthreads();
  }
  float maxLf = (float)(rs[0] >= 1 ? rs[0] : 1);
  int nRoots = nRootS;
  // top-32 rounds over compact root list: key = size*label, tie -> smaller label
  for (int r = 0; r < KCAP; r++){
    float bk = -1.0f; int blab = 0x7fffffff; int be = -1;
    for (int e = t; e < nRoots; e += 256){
      if ((used[e >> 5] >> (e & 31)) & 1u) continue;
      int i = rootIx[base + e];
      u32 v = runPack[base + i];
      int lab = ((int)((v >> 16) & 255)) * 256 + (int)(v & 255);
      float key = (float)runSz[base + i] * (float)lab;
      if (key > bk || (key == bk && lab < blab)){ bk = key; blab = lab; be = e; }
    }
    rk[t] = bk; ri[t] = blab; re[t] = be;
    __syncthreads();
    for (int off = 128; off > 0; off >>= 1){
      if (t < off && (rk[t+off] > rk[t] || (rk[t+off] == rk[t] && ri[t+off] < ri[t]))){
        rk[t] = rk[t+off]; ri[t] = ri[t+off]; re[t] = re[t+off];
      }
      __syncthreads();
    }
    if (t == 0){
      if (rk[0] > 0.0f && re[0] >= 0){
        int e = re[0];
        used[e >> 5] |= 1u << (e & 31);
        int i = rootIx[base + e];
        selRoot[r] = i;
        sSel[u*KCAP + r]     = rk[0] / maxLf;                 // (size*lab)/maxL
        scaleSel[u*KCAP + r] = (float)ri[0] / maxLf;
      } else {
        for (int q = r; q < KCAP; q++){
          sSel[u*KCAP + q] = 0.0f; scaleSel[u*KCAP + q] = 0.0f;
        }
        stop = 1;
      }
    }
    __syncthreads();
    if (stop) break;
  }
  // map each run to its selected comp index (high byte), 255 = unselected
  for (int i = t; i < NRc; i += 256){
    int r = runPar[base + i];
    int j = 255;
    #pragma unroll
    for (int jj = 0; jj < KCAP; jj++) if (selRoot[jj] == r) j = jj;
    runPack[base + i] = ((u32)j << 24) | (runPack[base + i] & 0x00FFFFFFu);
  }
  if (t == 0) runCnt[u] = NRc;
}

// ---------------- fused chain step: overlaps (run vs Pbm) + scan decisions + Pbm paint ----------------
__global__ __launch_bounds__(256) void k_chain(
    const u32* __restrict__ runPack, const int* __restrict__ runCnt,
    const float* __restrict__ sSel, const float* __restrict__ scaleSel,
    float* __restrict__ barP, float* __restrict__ barT,
    int* __restrict__ n24, float* __restrict__ scaleP,
    u64* __restrict__ Pbm, int kstep, int tval){
  int w = blockIdx.x, t = threadIdx.x;
  int pass = w / 12, s = w % 12;
  int u = (pass * 5 + kstep) * BC + s;
  __shared__ int cnt[KCAP*KCAP];
  __shared__ float spL[KCAP];
  __shared__ int add_dst[KCAP];
  __shared__ int bestA[KCAP];
  __shared__ float bvA[KCAP];
  __shared__ int nS;
  for (int i = t; i < KCAP*KCAP; i += 256) cnt[i] = 0;
  if (t < KCAP) spL[t] = scaleP[w*KCAP + t];
  if (t == 0) nS = n24[w];
  __syncthreads();
  int NR = runCnt[u];
  int n0 = nS;
  const u32* rp = runPack + (size_t)u * RUNCAP;
  const u64* Pb = Pbm + (size_t)w * KCAP * 1024;
  // OV counts: for each run of selected comp j, popc against stored comps k < n0
  for (int i = t; i < NR; i += 256){
    u32 v = rp[i];
    int j = v >> 24;
    if (j >= KCAP) continue;
    int row = (v >> 16) & 255, s0 = (v >> 8) & 255, E = v & 255;
    int w0 = s0 >> 6, w1 = E >> 6;
    for (int wi = w0; wi <= w1; wi++){
      int lo = max(s0, wi << 6), hi = min(E + 1, (wi << 6) + 64);
      u64 mask = (hi - lo == 64) ? ~0ull : ((((u64)1 << (hi - lo)) - 1) << (lo - (wi << 6)));
      int wofs = row * 4 + wi;
      for (int k = 0; k < n0; k++){
        int c = __popcll(Pb[(size_t)k * 1024 + wofs] & mask);
        if (c) atomicAdd(&cnt[j*KCAP + k], c);
      }
    }
  }
  __syncthreads();
  // per-j argmax over the full 32-wide OV row (entries k>=n0 are exactly 0)
  if (t < KCAP){
    float sn = scaleSel[(size_t)u*KCAP + t];
    int best = 0; float bv = 0.0f;
    if (sn > 0.0f){
      bv = (n0 > 0) ? sn * spL[0] * (float)cnt[t*KCAP + 0] : 0.0f;
      for (int k = 1; k < KCAP; k++){
        float ov = (k < n0) ? sn * spL[k] * (float)cnt[t*KCAP + k] : 0.0f;
        if (ov > bv){ bv = ov; best = k; }
      }
    }
    bestA[t] = best; bvA[t] = bv;
  }
  __syncthreads();
  // sequential decisions (mirrors lax.scan)
  if (t == 0){
    int n = n0;
    float* bar = (pass ? barT : barP) + (size_t)s * KCAP * MAXI;
    for (int j = 0; j < KCAP; j++){
      add_dst[j] = -1;
      float sv = scaleSel[(size_t)u*KCAP + j];
      if (sv <= 0.0f) continue;                    // invalid comp: no-op
      if (bvA[j] > 0.0f){                          // matched: overwrite stored slot
        bar[bestA[j]*MAXI + tval] = sSel[(size_t)u*KCAP + j];
      } else if (n < KCAP){                        // add new component
        bar[n*MAXI + tval] = sSel[(size_t)u*KCAP + j];
        scaleP[w*KCAP + n] = sv;
        add_dst[j] = n;
        n++;
      }
    }
    n24[w] = n;
  }
  __syncthreads();
  // zero Pbm slots for added comps
  for (int j = 0; j < KCAP; j++){
    int d = add_dst[j];
    if (d < 0) continue;
    u64* dst = Pbm + ((size_t)w*KCAP + d) * 1024;
    for (int x = t; x < 1024; x += 256) dst[x] = 0ull;
  }
  __syncthreads();
  // paint runs of added comps into Pbm
  for (int i = t; i < NR; i += 256){
    u32 v = rp[i];
    int j = v >> 24;
    if (j >= KCAP) continue;
    int d = add_dst[j];
    if (d < 0) continue;
    int row = (v >> 16) & 255, s0 = (v >> 8) & 255, E = v & 255;
    int w0 = s0 >> 6, w1 = E >> 6;
    u64* dst = Pbm + ((size_t)w*KCAP + d) * 1024 + row * 4;
    for (int wi = w0; wi <= w1; wi++){
      int lo = max(s0, wi << 6), hi = min(E + 1, (wi << 6) + 64);
      u64 mask = (hi - lo == 64) ? ~0ull : ((((u64)1 << (hi - lo)) - 1) << (lo - (wi << 6)));
      atomicOr(&dst[wi], mask);
    }
  }
}

// ---------------- final loss ----------------
__global__ void k_loss(const float* __restrict__ barP, const float* __restrict__ barT,
                       const int* __restrict__ n24, float* __restrict__ out){
  if (blockIdx.x != 0 || threadIdx.x != 0) return;
  float total = 0.0f;
  for (int s = 0; s < BC; s++){
    int np = n24[s], nt = n24[12 + s];
    for (int k = 0; k < KCAP; k++){
      if (k >= np) continue;
      const float* bp = barP + (s*KCAP + k)*MAXI;
      float pmax = bp[0];
      for (int t = 1; t < MAXI; t++) pmax = fmaxf(pmax, bp[t]);
      if (!(pmax > 0.0f)) pmax = 1.0f;
      float acc = 0.0f;
      for (int t = 0; t < MAXI; t++){
        float tv = (k < nt) ? barT[(s*KCAP + k)*MAXI + t] : 0.0f;
        float d = tv - bp[t];
        acc += d * d;
      }
      total += acc / (pmax * pmax);
    }
  }
  out[0] = total * 0.25f;   // mean over B=4
}

extern "C" void kernel_launch(void* const* d_in, const int* in_sizes, int n_in,
                              void* d_out, int out_size, void* d_ws, size_t ws_size,
                              hipStream_t stream){
  const float* pred = (const float*)d_in[0];
  const float* gum  = (const float*)d_in[1];
  const int*   tgt  = (const int*)d_in[2];
  float* out = (float*)d_out;
  char* ws = (char*)d_ws;
  size_t off = 0;
  auto alloc = [&](size_t bytes)->char*{
    char* p = ws + off;
    off += (bytes + 255) & ~(size_t)255;
    return p;
  };
  u64* bmAll   = (u64*)alloc((size_t)NSLOT*1024*8);         // 0.98 MB
  u32* runPack = (u32*)alloc((size_t)NSLOT*RUNCAP*4);       // 7.9 MB
  int* runPar  = (int*)alloc((size_t)NSLOT*RUNCAP*4);       // 7.9 MB
  int* runSz   = (int*)alloc((size_t)NSLOT*RUNCAP*4);       // 7.9 MB
  int* rootIx  = (int*)alloc((size_t)NSLOT*RUNCAP*4);       // 7.9 MB
  int* runCnt  = (int*)alloc(NSLOT*4);
  float* sSel     = (float*)alloc((size_t)NSLOT*KCAP*4);
  float* scaleSel = (float*)alloc((size_t)NSLOT*KCAP*4);
  u64* Pbm     = (u64*)alloc((size_t)NCH*KCAP*1024*8);      // 6.3 MB
  // contiguous zero region: barP | barT | scaleP | n24
  size_t zbytes = (size_t)(BC*KCAP*MAXI*2 + NCH*KCAP)*4 + NCH*4;
  char* zreg = alloc(zbytes);
  float* barP   = (float*)zreg;
  float* barT   = barP + BC*KCAP*MAXI;
  float* scaleP = barT + BC*KCAP*MAXI;
  int*   n24    = (int*)(scaleP + NCH*KCAP);
  if (off > ws_size) return;

  hipMemsetAsync(zreg, 0, zbytes, stream);
  // binarize both passes' base masks (steps g=0 and g=5)
  k_bin<<<(NB*HW)/256,256,0,stream>>>(pred, gum, tgt, bmAll);
  // morphology: e1/d1 from base, then e2/d2, both passes batched
  k_morph4<<<192,256,0,stream>>>(bmAll, bmAll, make_int4(0,0,5,5), make_int4(1,3,6,8), make_int4(1,0,1,0));
  k_morph4<<<192,256,0,stream>>>(bmAll, bmAll, make_int4(1,3,6,8), make_int4(2,4,7,9), make_int4(1,0,1,0));
  // run-based CC + selection over all 120 slots
  k_cc_runs<<<NSLOT,256,0,stream>>>(bmAll, runPack, runPar, runSz, rootIx, runCnt,
                                    sSel, scaleSel);
  // sequential matching chain: 5 steps, both passes per step
  const int tvals[5] = {2, 3, 4, 1, 0};
  for (int k = 0; k < 5; k++){
    k_chain<<<NCH,256,0,stream>>>(runPack, runCnt, sSel, scaleSel, barP, barT,
                                  n24, scaleP, Pbm, k, tvals[k]);
  }
  k_loss<<<1,64,0,stream>>>(barP, barT, n24, out);
}

// Round 7
// 549.942 us; speedup vs baseline: 3.3215x; 3.3215x over previous
//
#include <hip/hip_runtime.h>

#define NB 4
#define NC 3
#define BC 12
#define HW 65536
#define KCAP 32
#define MAXI 5
#define RUNCAP 16384
#define NSLOT 120     // 10 steps x 12 (b,c) slots
#define NCH 24        // chain slots: 2 passes x 12

typedef unsigned long long u64;
typedef unsigned int u32;

// ---------------- union-find (lock-free, link-to-MAX, path halving) ----------------
// root = MAX run index of the component -> root run holds the comp's max pixel.
__device__ __forceinline__ int uf_find(int* P, int x){
  while (true){
    int p = P[x];
    if (p == x) return x;
    int gp = P[p];
    if (gp == p) return p;
    P[x] = gp;   // path halving
    x = gp;
  }
}
__device__ __forceinline__ void uf_union_max(int* P, int a, int b){
  while (true){
    a = uf_find(P, a); b = uf_find(P, b);
    if (a == b) return;
    if (a > b){ int t = a; a = b; b = t; }   // a < b: link smaller root to larger
    int old = atomicCAS(&P[a], a, b);
    if (old == a) return;
    a = old;
  }
}

// walk runs of a 256-bit row (4 u64 words); emit(start, end_exclusive)
template<typename F>
__device__ __forceinline__ void walk_runs(const u64* wv, F&& emit){
  int open_s = -1;
  #pragma unroll
  for (int wi = 0; wi < 4; wi++){
    u64 v = wv[wi];
    int base = wi << 6;
    int pos = 0;
    while (pos < 64){
      u64 rem = v >> pos;
      if (open_s >= 0){
        u64 nz = ~rem;
        int z = nz ? __builtin_ctzll(nz) : 64;     // first zero at/after pos
        if (z >= 64 - pos){ pos = 64; }            // run continues past word
        else { emit(open_s, base + pos + z); open_s = -1; pos += z; }
      } else {
        if (rem == 0ull){ pos = 64; }
        else {
          int o = __builtin_ctzll(rem);            // first one
          open_s = base + pos + o;
          pos += o;
        }
      }
    }
  }
  if (open_s >= 0) emit(open_s, 256);
}

// ---------------- binarization: both base masks (pred -> g=0, tgt -> g=5) ----------------
__global__ void k_bin(const float* __restrict__ pred, const float* __restrict__ gum,
                      const int* __restrict__ tgt, u64* __restrict__ bmAll){
  int g = blockIdx.x * 256 + threadIdx.x;    // NB*HW threads
  int b = g >> 16, p = g & (HW - 1);
  size_t base = (size_t)b * NC * HW + p;
  float v0 = pred[base]        + gum[base];
  float v1 = pred[base + HW]   + gum[base + HW];
  float v2 = pred[base + 2*HW] + gum[base + 2*HW];
  int a = 0; float m = v0;
  if (v1 > m){ m = v1; a = 1; }
  if (v2 > m){ m = v2; a = 2; }
  int tg = tgt[(size_t)b * HW + p];
  u64 p0 = __ballot(a == 0), p1 = __ballot(a == 1), p2 = __ballot(a == 2);
  u64 t0 = __ballot(tg == 0), t1 = __ballot(tg == 1), t2 = __ballot(tg == 2);
  if ((threadIdx.x & 63) == 0){
    int w = p >> 6;
    int sp = b * NC;                       // pass0 base: step g=0
    bmAll[(size_t)(sp + 0) * 1024 + w] = p0;
    bmAll[(size_t)(sp + 1) * 1024 + w] = p1;
    bmAll[(size_t)(sp + 2) * 1024 + w] = p2;
    int st = 60 + b * NC;                  // pass1 base: step g=5
    bmAll[(size_t)(st + 0) * 1024 + w] = t0;
    bmAll[(size_t)(st + 1) * 1024 + w] = t1;
    bmAll[(size_t)(st + 2) * 1024 + w] = t2;
  }
}

// ---------------- 5x5 morphology on bitmaps: 4 independent jobs per launch ----------------
__global__ void k_morph4(const u64* __restrict__ bmAll, u64* __restrict__ bmAllW,
                         int4 srcs, int4 dsts, int4 flgs){
  int t = blockIdx.x * 256 + threadIdx.x;  // 4 * 12 * 1024 = 49152
  int job = t / 12288, rest = t % 12288;
  int s = rest >> 10, word = rest & 1023;
  int row = word >> 2, w = word & 3;
  int srcG = job == 0 ? srcs.x : job == 1 ? srcs.y : job == 2 ? srcs.z : srcs.w;
  int dstG = job == 0 ? dsts.x : job == 1 ? dsts.y : job == 2 ? dsts.z : dsts.w;
  int er   = job == 0 ? flgs.x : job == 1 ? flgs.y : job == 2 ? flgs.z : flgs.w;
  const u64* bs = bmAll + (size_t)(srcG * BC + s) * 1024;
  u64 res = er ? ~0ull : 0ull;
  for (int dy = -2; dy <= 2; dy++){
    int y = row + dy;
    if (y < 0 || y > 255){ if (er) res = 0; continue; }
    const u64* rw = bs + y * 4;
    u64 m = rw[w];
    u64 l = (w > 0) ? rw[w-1] : 0ull;
    u64 r = (w < 3) ? rw[w+1] : 0ull;
    u64 x1l = (m << 1) | (l >> 63);
    u64 x2l = (m << 2) | (l >> 62);
    u64 x1r = (m >> 1) | (r << 63);
    u64 x2r = (m >> 2) | (r << 62);
    u64 h = er ? (m & x1l & x2l & x1r & x2r) : (m | x1l | x2l | x1r | x2r);
    res = er ? (res & h) : (res | h);
  }
  bmAllW[(size_t)(dstG * BC + s) * 1024 + word] = res;
}

// ---------------- run-based CC in LDS + aggregation + top-32 selection, one block/slot ----------------
// par (64KB) + pkz (64KB: run extents during union, then per-root sizes) in LDS.
__global__ __launch_bounds__(256) void k_cc_runs(
    const u64* __restrict__ bmAll, u32* __restrict__ runPack, u32* __restrict__ rootPk,
    int* __restrict__ runCnt, float* __restrict__ sSel, float* __restrict__ scaleSel){
  __shared__ int par[RUNCAP];      // 64 KB
  __shared__ u32 pkz[RUNCAP];      // 64 KB: pk during union phase, sizes afterwards
  __shared__ int rs[257];
  __shared__ u32 used[RUNCAP/32];  // 2 KB
  __shared__ int selRoot[KCAP];
  __shared__ float rk[256];
  __shared__ int ri[256], re[256];
  __shared__ int stop, nRootS, lmS;
  int u = blockIdx.x, t = threadIdx.x;     // thread t = row t
  u64 wv[4];
  const u64* bp = bmAll + (size_t)u * 1024 + t * 4;
  #pragma unroll
  for (int i = 0; i < 4; i++) wv[i] = bp[i];
  int nr = 0;
  walk_runs(wv, [&](int a, int b){ (void)a; (void)b; nr++; });
  rs[t] = nr;
  if (t == 0){ stop = 0; nRootS = 0; lmS = 0; }
  __syncthreads();
  // inclusive Hillis-Steele scan of run counts
  for (int d = 1; d < 256; d <<= 1){
    int add = (t >= d) ? rs[t - d] : 0;
    __syncthreads();
    rs[t] += add;
    __syncthreads();
  }
  int incl = rs[t];
  __syncthreads();
  rs[t] = incl - nr;                 // exclusive offset (my base)
  if (t == 255) rs[256] = incl;      // total
  __syncthreads();
  int NR = rs[256];
  int NRc = NR < RUNCAP ? NR : RUNCAP;
  int myBase = rs[t];
  size_t base = (size_t)u * RUNCAP;
  for (int i = t; i < RUNCAP; i += 256) par[i] = i;
  // emit runs: LDS pk + global copy (global needed by k_chain and aggregation re-read)
  {
    int o = myBase;
    walk_runs(wv, [&](int a, int b){
      if (o < RUNCAP){
        u32 v = ((u32)t << 16) | ((u32)a << 8) | (u32)(b - 1);
        pkz[o] = v;
        runPack[base + o] = 0xFF000000u | v;
      }
      o++;
    });
  }
  __syncthreads();
  // seam unions row t vs t-1: linear two-pointer merge sweep over sorted run lists.
  // match iff s1 <= E2+1 && s2 <= E1+1 (8-connectivity). Advance smaller right end:
  // prev right = E1, cur(expanded) right = E2+1; E1 <= E2 -> advance j else i.
  // Safe: same-row runs are disjoint with gap>=1, so no pair is skipped.
  if (t >= 1 && myBase < RUNCAP){
    int iEnd = myBase + nr; if (iEnd > RUNCAP) iEnd = RUNCAP;
    int j = rs[t-1], jEnd = myBase;
    int i = myBase;
    while (i < iEnd && j < jEnd){
      u32 a = pkz[i], b = pkz[j];
      int s2 = (a >> 8) & 255, E2 = (int)(a & 255);
      int s1 = (b >> 8) & 255, E1 = (int)(b & 255);
      if (s1 <= E2 + 1 && s2 <= E1 + 1) uf_union_max(par, i, j);
      if (E1 <= E2) j++; else i++;
    }
  }
  __syncthreads();
  // flatten
  for (int i = t; i < NRc; i += 256){
    int r = i, p = par[r];
    while (p != r){ r = p; p = par[r]; }
    par[i] = r;
  }
  __syncthreads();
  // repurpose pkz as per-root size accumulator
  for (int i = t; i < NRc; i += 256) pkz[i] = 0;
  for (int i = t; i < RUNCAP/32; i += 256) used[i] = 0;
  if (t < KCAP) selRoot[t] = -1;
  __syncthreads();
  // aggregate: sizes per root (LDS), compact roots with label>0, global max fg pixel
  int lm = 0;
  for (int i = t; i < NRc; i += 256){
    u32 v = runPack[base + i];
    int row = (v >> 16) & 255, s0 = (v >> 8) & 255, E = (int)(v & 255);
    int r = par[i];
    atomicAdd((int*)&pkz[r], E - s0 + 1);
    int pix = row * 256 + E;
    lm = max(lm, pix);
    if (r == i && pix > 0){               // root run holds comp's max pixel (= label)
      int pos = atomicAdd(&nRootS, 1);
      rootPk[base + pos] = ((u32)pix << 14) | (u32)i;   // pix:16b | runIdx:14b
    }
  }
  atomicMax(&lmS, lm);
  __syncthreads();
  float maxLf = (float)(lmS >= 1 ? lmS : 1);
  int nRoots = nRootS;
  // top-32 rounds over compact root list: key = size*label, tie -> smaller label
  for (int r = 0; r < KCAP; r++){
    float bk = -1.0f; int blab = 0x7fffffff; int be = -1;
    for (int e = t; e < nRoots; e += 256){
      if ((used[e >> 5] >> (e & 31)) & 1u) continue;
      u32 v = rootPk[base + e];
      int lab = (int)(v >> 14);
      int i = (int)(v & 16383);
      float key = (float)(int)pkz[i] * (float)lab;
      if (key > bk || (key == bk && lab < blab)){ bk = key; blab = lab; be = e; }
    }
    rk[t] = bk; ri[t] = blab; re[t] = be;
    __syncthreads();
    for (int off = 128; off > 0; off >>= 1){
      if (t < off && (rk[t+off] > rk[t] || (rk[t+off] == rk[t] && ri[t+off] < ri[t]))){
        rk[t] = rk[t+off]; ri[t] = ri[t+off]; re[t] = re[t+off];
      }
      __syncthreads();
    }
    if (t == 0){
      if (rk[0] > 0.0f && re[0] >= 0){
        int e = re[0];
        used[e >> 5] |= 1u << (e & 31);
        selRoot[r] = (int)(rootPk[base + e] & 16383);
        sSel[u*KCAP + r]     = rk[0] / maxLf;               // (size*lab)/maxL
        scaleSel[u*KCAP + r] = (float)ri[0] / maxLf;
      } else {
        for (int q = r; q < KCAP; q++){
          sSel[u*KCAP + q] = 0.0f; scaleSel[u*KCAP + q] = 0.0f;
        }
        stop = 1;
      }
    }
    __syncthreads();
    if (stop) break;
  }
  // map each run to its selected comp index (high byte), 255 = unselected
  for (int i = t; i < NRc; i += 256){
    int r = par[i];
    int j = 255;
    #pragma unroll
    for (int jj = 0; jj < KCAP; jj++) if (selRoot[jj] == r) j = jj;
    u32 v = runPack[base + i];
    runPack[base + i] = ((u32)j << 24) | (v & 0x00FFFFFFu);
  }
  if (t == 0) runCnt[u] = NRc;
}

// ---------------- fused chain step: overlaps (run vs Pbm) + scan decisions + Pbm paint ----------------
__global__ __launch_bounds__(256) void k_chain(
    const u32* __restrict__ runPack, const int* __restrict__ runCnt,
    const float* __restrict__ sSel, const float* __restrict__ scaleSel,
    float* __restrict__ barP, float* __restrict__ barT,
    int* __restrict__ n24, float* __restrict__ scaleP,
    u64* __restrict__ Pbm, int kstep, int tval){
  int w = blockIdx.x, t = threadIdx.x;
  int pass = w / 12, s = w % 12;
  int u = (pass * 5 + kstep) * BC + s;
  __shared__ int cnt[KCAP*KCAP];
  __shared__ float spL[KCAP];
  __shared__ int add_dst[KCAP];
  __shared__ int bestA[KCAP];
  __shared__ float bvA[KCAP];
  __shared__ int nS;
  for (int i = t; i < KCAP*KCAP; i += 256) cnt[i] = 0;
  if (t < KCAP) spL[t] = scaleP[w*KCAP + t];
  if (t == 0) nS = n24[w];
  __syncthreads();
  int NR = runCnt[u];
  int n0 = nS;
  const u32* rp = runPack + (size_t)u * RUNCAP;
  const u64* Pb = Pbm + (size_t)w * KCAP * 1024;
  // OV counts: for each run of selected comp j, popc against stored comps k < n0
  for (int i = t; i < NR; i += 256){
    u32 v = rp[i];
    int j = v >> 24;
    if (j >= KCAP) continue;
    int row = (v >> 16) & 255, s0 = (v >> 8) & 255, E = v & 255;
    int w0 = s0 >> 6, w1 = E >> 6;
    for (int wi = w0; wi <= w1; wi++){
      int lo = max(s0, wi << 6), hi = min(E + 1, (wi << 6) + 64);
      u64 mask = (hi - lo == 64) ? ~0ull : ((((u64)1 << (hi - lo)) - 1) << (lo - (wi << 6)));
      int wofs = row * 4 + wi;
      for (int k = 0; k < n0; k++){
        int c = __popcll(Pb[(size_t)k * 1024 + wofs] & mask);
        if (c) atomicAdd(&cnt[j*KCAP + k], c);
      }
    }
  }
  __syncthreads();
  // per-j argmax over the full 32-wide OV row (entries k>=n0 are exactly 0)
  if (t < KCAP){
    float sn = scaleSel[(size_t)u*KCAP + t];
    int best = 0; float bv = 0.0f;
    if (sn > 0.0f){
      bv = (n0 > 0) ? sn * spL[0] * (float)cnt[t*KCAP + 0] : 0.0f;
      for (int k = 1; k < KCAP; k++){
        float ov = (k < n0) ? sn * spL[k] * (float)cnt[t*KCAP + k] : 0.0f;
        if (ov > bv){ bv = ov; best = k; }
      }
    }
    bestA[t] = best; bvA[t] = bv;
  }
  __syncthreads();
  // sequential decisions (mirrors lax.scan)
  if (t == 0){
    int n = n0;
    float* bar = (pass ? barT : barP) + (size_t)s * KCAP * MAXI;
    for (int j = 0; j < KCAP; j++){
      add_dst[j] = -1;
      float sv = scaleSel[(size_t)u*KCAP + j];
      if (sv <= 0.0f) continue;                    // invalid comp: no-op
      if (bvA[j] > 0.0f){                          // matched: overwrite stored slot
        bar[bestA[j]*MAXI + tval] = sSel[(size_t)u*KCAP + j];
      } else if (n < KCAP){                        // add new component
        bar[n*MAXI + tval] = sSel[(size_t)u*KCAP + j];
        scaleP[w*KCAP + n] = sv;
        add_dst[j] = n;
        n++;
      }
    }
    n24[w] = n;
  }
  __syncthreads();
  // zero Pbm slots for added comps
  for (int j = 0; j < KCAP; j++){
    int d = add_dst[j];
    if (d < 0) continue;
    u64* dst = Pbm + ((size_t)w*KCAP + d) * 1024;
    for (int x = t; x < 1024; x += 256) dst[x] = 0ull;
  }
  __syncthreads();
  // paint runs of added comps into Pbm
  for (int i = t; i < NR; i += 256){
    u32 v = rp[i];
    int j = v >> 24;
    if (j >= KCAP) continue;
    int d = add_dst[j];
    if (d < 0) continue;
    int row = (v >> 16) & 255, s0 = (v >> 8) & 255, E = v & 255;
    int w0 = s0 >> 6, w1 = E >> 6;
    u64* dst = Pbm + ((size_t)w*KCAP + d) * 1024 + row * 4;
    for (int wi = w0; wi <= w1; wi++){
      int lo = max(s0, wi << 6), hi = min(E + 1, (wi << 6) + 64);
      u64 mask = (hi - lo == 64) ? ~0ull : ((((u64)1 << (hi - lo)) - 1) << (lo - (wi << 6)));
      atomicOr(&dst[wi], mask);
    }
  }
}

// ---------------- final loss ----------------
__global__ void k_loss(const float* __restrict__ barP, const float* __restrict__ barT,
                       const int* __restrict__ n24, float* __restrict__ out){
  if (blockIdx.x != 0 || threadIdx.x != 0) return;
  float total = 0.0f;
  for (int s = 0; s < BC; s++){
    int np = n24[s], nt = n24[12 + s];
    for (int k = 0; k < KCAP; k++){
      if (k >= np) continue;
      const float* bp = barP + (s*KCAP + k)*MAXI;
      float pmax = bp[0];
      for (int t = 1; t < MAXI; t++) pmax = fmaxf(pmax, bp[t]);
      if (!(pmax > 0.0f)) pmax = 1.0f;
      float acc = 0.0f;
      for (int t = 0; t < MAXI; t++){
        float tv = (k < nt) ? barT[(s*KCAP + k)*MAXI + t] : 0.0f;
        float d = tv - bp[t];
        acc += d * d;
      }
      total += acc / (pmax * pmax);
    }
  }
  out[0] = total * 0.25f;   // mean over B=4
}

extern "C" void kernel_launch(void* const* d_in, const int* in_sizes, int n_in,
                              void* d_out, int out_size, void* d_ws, size_t ws_size,
                              hipStream_t stream){
  const float* pred = (const float*)d_in[0];
  const float* gum  = (const float*)d_in[1];
  const int*   tgt  = (const int*)d_in[2];
  float* out = (float*)d_out;
  char* ws = (char*)d_ws;
  size_t off = 0;
  auto alloc = [&](size_t bytes)->char*{
    char* p = ws + off;
    off += (bytes + 255) & ~(size_t)255;
    return p;
  };
  u64* bmAll   = (u64*)alloc((size_t)NSLOT*1024*8);         // 0.98 MB
  u32* runPack = (u32*)alloc((size_t)NSLOT*RUNCAP*4);       // 7.9 MB
  u32* rootPk  = (u32*)alloc((size_t)NSLOT*RUNCAP*4);       // 7.9 MB
  int* runCnt  = (int*)alloc(NSLOT*4);
  float* sSel     = (float*)alloc((size_t)NSLOT*KCAP*4);
  float* scaleSel = (float*)alloc((size_t)NSLOT*KCAP*4);
  u64* Pbm     = (u64*)alloc((size_t)NCH*KCAP*1024*8);      // 6.3 MB
  // contiguous zero region: barP | barT | scaleP | n24
  size_t zbytes = (size_t)(BC*KCAP*MAXI*2 + NCH*KCAP)*4 + NCH*4;
  char* zreg = alloc(zbytes);
  float* barP   = (float*)zreg;
  float* barT   = barP + BC*KCAP*MAXI;
  float* scaleP = barT + BC*KCAP*MAXI;
  int*   n24    = (int*)(scaleP + NCH*KCAP);
  if (off > ws_size) return;

  hipMemsetAsync(zreg, 0, zbytes, stream);
  // binarize both passes' base masks (steps g=0 and g=5)
  k_bin<<<(NB*HW)/256,256,0,stream>>>(pred, gum, tgt, bmAll);
  // morphology: e1/d1 from base, then e2/d2, both passes batched
  k_morph4<<<192,256,0,stream>>>(bmAll, bmAll, make_int4(0,0,5,5), make_int4(1,3,6,8), make_int4(1,0,1,0));
  k_morph4<<<192,256,0,stream>>>(bmAll, bmAll, make_int4(1,3,6,8), make_int4(2,4,7,9), make_int4(1,0,1,0));
  // run-based CC + selection over all 120 slots
  k_cc_runs<<<NSLOT,256,0,stream>>>(bmAll, runPack, rootPk, runCnt, sSel, scaleSel);
  // sequential matching chain: 5 steps, both passes per step
  const int tvals[5] = {2, 3, 4, 1, 0};
  for (int k = 0; k < 5; k++){
    k_chain<<<NCH,256,0,stream>>>(runPack, runCnt, sSel, scaleSel, barP, barT,
                                  n24, scaleP, Pbm, k, tvals[k]);
  }
  k_loss<<<1,64,0,stream>>>(barP, barT, n24, out);
}

// Round 8
// 397.804 us; speedup vs baseline: 4.5918x; 1.3824x over previous
//
#include <hip/hip_runtime.h>

#define NB 4
#define NC 3
#define BC 12
#define HW 65536
#define KCAP 32
#define MAXI 5
#define RUNCAP 16384
#define NSLOT 120     // 10 steps x 12 (b,c) slots
#define NCH 24        // chain slots: 2 passes x 12
#define REGQ 24       // cached root entries per thread (24*256 = 6144)
#define REGTOT (REGQ*256)

typedef unsigned long long u64;
typedef unsigned int u32;

// ---------------- union-find (lock-free, link-to-MAX, path halving) ----------------
// root = MAX run index of the component -> root run holds the comp's max pixel.
__device__ __forceinline__ int uf_find(int* P, int x){
  while (true){
    int p = P[x];
    if (p == x) return x;
    int gp = P[p];
    if (gp == p) return p;
    P[x] = gp;   // path halving
    x = gp;
  }
}
__device__ __forceinline__ void uf_union_max(int* P, int a, int b){
  while (true){
    a = uf_find(P, a); b = uf_find(P, b);
    if (a == b) return;
    if (a > b){ int t = a; a = b; b = t; }   // a < b: link smaller root to larger
    int old = atomicCAS(&P[a], a, b);
    if (old == a) return;
    a = old;
  }
}

// walk runs of a 256-bit row (4 u64 words); emit(start, end_exclusive)
template<typename F>
__device__ __forceinline__ void walk_runs(const u64* wv, F&& emit){
  int open_s = -1;
  #pragma unroll
  for (int wi = 0; wi < 4; wi++){
    u64 v = wv[wi];
    int base = wi << 6;
    int pos = 0;
    while (pos < 64){
      u64 rem = v >> pos;
      if (open_s >= 0){
        u64 nz = ~rem;
        int z = nz ? __builtin_ctzll(nz) : 64;     // first zero at/after pos
        if (z >= 64 - pos){ pos = 64; }            // run continues past word
        else { emit(open_s, base + pos + z); open_s = -1; pos += z; }
      } else {
        if (rem == 0ull){ pos = 64; }
        else {
          int o = __builtin_ctzll(rem);            // first one
          open_s = base + pos + o;
          pos += o;
        }
      }
    }
  }
  if (open_s >= 0) emit(open_s, 256);
}

// ---------------- binarization: both base masks (pred -> g=0, tgt -> g=5) ----------------
__global__ void k_bin(const float* __restrict__ pred, const float* __restrict__ gum,
                      const int* __restrict__ tgt, u64* __restrict__ bmAll){
  int g = blockIdx.x * 256 + threadIdx.x;    // NB*HW threads
  int b = g >> 16, p = g & (HW - 1);
  size_t base = (size_t)b * NC * HW + p;
  float v0 = pred[base]        + gum[base];
  float v1 = pred[base + HW]   + gum[base + HW];
  float v2 = pred[base + 2*HW] + gum[base + 2*HW];
  int a = 0; float m = v0;
  if (v1 > m){ m = v1; a = 1; }
  if (v2 > m){ m = v2; a = 2; }
  int tg = tgt[(size_t)b * HW + p];
  u64 p0 = __ballot(a == 0), p1 = __ballot(a == 1), p2 = __ballot(a == 2);
  u64 t0 = __ballot(tg == 0), t1 = __ballot(tg == 1), t2 = __ballot(tg == 2);
  if ((threadIdx.x & 63) == 0){
    int w = p >> 6;
    int sp = b * NC;                       // pass0 base: step g=0
    bmAll[(size_t)(sp + 0) * 1024 + w] = p0;
    bmAll[(size_t)(sp + 1) * 1024 + w] = p1;
    bmAll[(size_t)(sp + 2) * 1024 + w] = p2;
    int st = 60 + b * NC;                  // pass1 base: step g=5
    bmAll[(size_t)(st + 0) * 1024 + w] = t0;
    bmAll[(size_t)(st + 1) * 1024 + w] = t1;
    bmAll[(size_t)(st + 2) * 1024 + w] = t2;
  }
}

// ---------------- 5x5 morphology on bitmaps: 4 independent jobs per launch ----------------
__global__ void k_morph4(const u64* __restrict__ bmAll, u64* __restrict__ bmAllW,
                         int4 srcs, int4 dsts, int4 flgs){
  int t = blockIdx.x * 256 + threadIdx.x;  // 4 * 12 * 1024 = 49152
  int job = t / 12288, rest = t % 12288;
  int s = rest >> 10, word = rest & 1023;
  int row = word >> 2, w = word & 3;
  int srcG = job == 0 ? srcs.x : job == 1 ? srcs.y : job == 2 ? srcs.z : srcs.w;
  int dstG = job == 0 ? dsts.x : job == 1 ? dsts.y : job == 2 ? dsts.z : dsts.w;
  int er   = job == 0 ? flgs.x : job == 1 ? flgs.y : job == 2 ? flgs.z : flgs.w;
  const u64* bs = bmAll + (size_t)(srcG * BC + s) * 1024;
  u64 res = er ? ~0ull : 0ull;
  for (int dy = -2; dy <= 2; dy++){
    int y = row + dy;
    if (y < 0 || y > 255){ if (er) res = 0; continue; }
    const u64* rw = bs + y * 4;
    u64 m = rw[w];
    u64 l = (w > 0) ? rw[w-1] : 0ull;
    u64 r = (w < 3) ? rw[w+1] : 0ull;
    u64 x1l = (m << 1) | (l >> 63);
    u64 x2l = (m << 2) | (l >> 62);
    u64 x1r = (m >> 1) | (r << 63);
    u64 x2r = (m >> 2) | (r << 62);
    u64 h = er ? (m & x1l & x2l & x1r & x2r) : (m | x1l | x2l | x1r | x2r);
    res = er ? (res & h) : (res | h);
  }
  bmAllW[(size_t)(dstG * BC + s) * 1024 + word] = res;
}

// ---------------- run-based CC in LDS + register-cached top-32 selection, one block/slot ----
// Outputs: compact selected-run list (selRuns = rootPk reuse), selCnt, sSel, scaleSel.
__global__ __launch_bounds__(256) void k_cc_runs(
    const u64* __restrict__ bmAll, u32* __restrict__ rootPk /* -> selRuns */,
    int* __restrict__ selCnt, float* __restrict__ sSel, float* __restrict__ scaleSel){
  __shared__ int par[RUNCAP];      // 64 KB
  __shared__ u32 pkz[RUNCAP];      // 64 KB: pk -> sizes -> root->j map
  __shared__ int rs[257];
  __shared__ u32 used[RUNCAP/32];  // 2 KB (fallback only)
  __shared__ int selRoot[KCAP];
  __shared__ u64 wred[4];
  __shared__ u64 bestS;
  __shared__ int nRootS, lmS, nSelS;
  int u = blockIdx.x, t = threadIdx.x;     // thread t = row t
  u64 wv[4];
  const u64* bp = bmAll + (size_t)u * 1024 + t * 4;
  #pragma unroll
  for (int i = 0; i < 4; i++) wv[i] = bp[i];
  int nr = 0;
  walk_runs(wv, [&](int a, int b){ (void)a; (void)b; nr++; });
  rs[t] = nr;
  if (t == 0){ nRootS = 0; lmS = 0; nSelS = 0; }
  if (t < KCAP) selRoot[t] = -1;
  for (int i = t; i < RUNCAP/32; i += 256) used[i] = 0;
  __syncthreads();
  // inclusive Hillis-Steele scan of run counts
  for (int d = 1; d < 256; d <<= 1){
    int add = (t >= d) ? rs[t - d] : 0;
    __syncthreads();
    rs[t] += add;
    __syncthreads();
  }
  int incl = rs[t];
  __syncthreads();
  rs[t] = incl - nr;                 // exclusive offset (my base)
  if (t == 255) rs[256] = incl;      // total
  __syncthreads();
  int NR = rs[256];
  int NRc = NR < RUNCAP ? NR : RUNCAP;
  int myBase = rs[t];
  size_t base = (size_t)u * RUNCAP;
  for (int i = t; i < NRc; i += 256) par[i] = i;
  // emit pk into LDS (for seam sweep)
  {
    int o = myBase;
    walk_runs(wv, [&](int a, int b){
      if (o < RUNCAP) pkz[o] = ((u32)t << 16) | ((u32)a << 8) | (u32)(b - 1);
      o++;
    });
  }
  __syncthreads();
  // seam unions row t vs t-1: linear two-pointer merge (8-connectivity |dx|<=1).
  if (t >= 1 && myBase < RUNCAP){
    int iEnd = myBase + nr; if (iEnd > RUNCAP) iEnd = RUNCAP;
    int j = rs[t-1], jEnd = myBase;
    int i = myBase;
    while (i < iEnd && j < jEnd){
      u32 a = pkz[i], b = pkz[j];
      int s2 = (a >> 8) & 255, E2 = (int)(a & 255);
      int s1 = (b >> 8) & 255, E1 = (int)(b & 255);
      if (s1 <= E2 + 1 && s2 <= E1 + 1) uf_union_max(par, i, j);
      if (E1 <= E2) j++; else i++;
    }
  }
  __syncthreads();
  // flatten
  for (int i = t; i < NRc; i += 256){
    int r = i, p = par[r];
    while (p != r){ r = p; p = par[r]; }
    par[i] = r;
  }
  __syncthreads();
  // pkz -> per-root sizes
  for (int i = t; i < NRc; i += 256) pkz[i] = 0;
  __syncthreads();
  // aggregate via re-walk of own row (no global pk storage)
  {
    int o = myBase, lm = 0;
    walk_runs(wv, [&](int a, int b){
      if (o < RUNCAP){
        int r = par[o];
        atomicAdd((int*)&pkz[r], b - a);
        int pix = t * 256 + (b - 1);
        lm = max(lm, pix);
        if (r == o && pix > 0){              // root run holds comp max pixel (= label)
          int pos = atomicAdd(&nRootS, 1);
          rootPk[base + pos] = ((u32)pix << 14) | (u32)o;   // pix:16b | runIdx:14b
        }
      }
      o++;
    });
    atomicMax(&lmS, lm);
  }
  __syncthreads();
  float maxLf = (float)(lmS >= 1 ? lmS : 1);
  int nRoots = nRootS;
  // ---- register cache: each thread holds <=REGQ packed keys ----
  // u64 key: f32bits(size*lab)<<32 | (0xFFFF-lab)<<16 | id. Labels unique => total order.
  u64 myKeys[REGQ];
  #pragma unroll
  for (int q = 0; q < REGQ; q++){
    myKeys[q] = 0;
    int e = q * 256 + t;
    if (e < nRoots){
      u32 v = rootPk[base + e];
      int lab = (int)(v >> 14);
      int i = (int)(v & 16383);
      float key = (float)(int)pkz[i] * (float)lab;
      myKeys[q] = ((u64)__float_as_uint(key) << 32) | ((u64)(0xFFFFu - (u32)lab) << 16)
                | ((u64)q << 8) | (u64)t;          // id: q(5b)<<8 | tid(8b), bit15=0
    }
  }
  // ---- 32 selection rounds, register scan + wave/LDS u64-max reduce ----
  for (int r = 0; r < KCAP; r++){
    u64 b = 0;
    #pragma unroll
    for (int q = 0; q < REGQ; q++) b = (myKeys[q] > b) ? myKeys[q] : b;
    if (nRoots > REGTOT){                           // rare fallback: scan tail from global
      for (int e = REGTOT + t; e < nRoots; e += 256){
        if ((used[e >> 5] >> (e & 31)) & 1u) continue;
        u32 v = rootPk[base + e];
        int lab = (int)(v >> 14);
        int i = (int)(v & 16383);
        float key = (float)(int)pkz[i] * (float)lab;
        u64 cand = ((u64)__float_as_uint(key) << 32) | ((u64)(0xFFFFu - (u32)lab) << 16)
                 | 0x8000u | (u64)e;                // bit15=1, e:14b
        b = (cand > b) ? cand : b;
      }
    }
    #pragma unroll
    for (int off = 32; off > 0; off >>= 1){
      u64 o = __shfl_xor(b, off);
      b = (o > b) ? o : b;
    }
    if ((t & 63) == 0) wred[t >> 6] = b;
    __syncthreads();
    if (t == 0){
      u64 m = wred[0];
      m = (wred[1] > m) ? wred[1] : m;
      m = (wred[2] > m) ? wred[2] : m;
      m = (wred[3] > m) ? wred[3] : m;
      bestS = m;
    }
    __syncthreads();
    u64 bestAll = bestS;
    if (bestAll == 0){
      if (t == 0){
        for (int q = r; q < KCAP; q++){ sSel[u*KCAP + q] = 0.0f; scaleSel[u*KCAP + q] = 0.0f; }
      }
      break;
    }
    if (!(bestAll & 0x8000u)){
      #pragma unroll
      for (int q = 0; q < REGQ; q++) if (myKeys[q] == bestAll) myKeys[q] = 0;
    }
    if (t == 0){
      int e;
      if (bestAll & 0x8000u){
        e = (int)(bestAll & 0x3FFF);
        used[e >> 5] |= 1u << (e & 31);
      } else {
        e = (int)((bestAll >> 8) & 0x1F) * 256 + (int)(bestAll & 0xFF);
      }
      int lab = 0xFFFF - (int)((bestAll >> 16) & 0xFFFF);
      selRoot[r] = (int)(rootPk[base + e] & 16383);
      sSel[u*KCAP + r]     = __uint_as_float((u32)(bestAll >> 32)) / maxLf;
      scaleSel[u*KCAP + r] = (float)lab / maxLf;
    }
    __syncthreads();
  }
  __syncthreads();
  // ---- pkz -> root->j map; emit compact selected runs into rootPk (selRuns) ----
  for (int i = t; i < NRc; i += 256) pkz[i] = 255u;
  __syncthreads();
  if (t < KCAP && selRoot[t] >= 0) pkz[selRoot[t]] = (u32)t;
  __syncthreads();
  {
    int o = myBase;
    walk_runs(wv, [&](int a, int b){
      if (o < RUNCAP){
        u32 j = pkz[par[o]];
        if (j < KCAP){
          int pos = atomicAdd(&nSelS, 1);
          rootPk[base + pos] = (j << 24) | ((u32)t << 16) | ((u32)a << 8) | (u32)(b - 1);
        }
      }
      o++;
    });
  }
  __syncthreads();
  if (t == 0) selCnt[u] = nSelS;
}

// ---------------- full matching chain: 5 steps in one kernel, one block per (pass,slot) ----
__global__ __launch_bounds__(1024) void k_chainall(
    const u32* __restrict__ selRuns, const int* __restrict__ selCnt,
    const float* __restrict__ sSel, const float* __restrict__ scaleSel,
    float* __restrict__ barP, float* __restrict__ barT,
    int* __restrict__ n24, u64* __restrict__ Pbm){
  int w = blockIdx.x, t = threadIdx.x;
  int pass = w / 12, s = w % 12;
  __shared__ int cnt[KCAP*KCAP];
  __shared__ float spL[KCAP];
  __shared__ int add_dst[KCAP];
  __shared__ int bestA[KCAP];
  __shared__ float bvA[KCAP];
  __shared__ int nS;
  if (t < KCAP) spL[t] = 0.0f;
  if (t == 0) nS = 0;
  float* bar = (pass ? barT : barP) + (size_t)s * KCAP * MAXI;
  u64* Pb = Pbm + (size_t)w * KCAP * 1024;
  #pragma unroll 1
  for (int st = 0; st < 5; st++){
    int u = (pass * 5 + st) * BC + s;
    int tval = (st < 3) ? st + 2 : (st == 3 ? 1 : 0);   // schedule {2,3,4,1,0}
    for (int i = t; i < KCAP*KCAP; i += 1024) cnt[i] = 0;
    __syncthreads();
    int n0 = nS;
    int NS = selCnt[u];
    const u32* rp = selRuns + (size_t)u * RUNCAP;
    // OV counts: each selected run vs stored comps k < n0
    for (int i = t; i < NS; i += 1024){
      u32 v = rp[i];
      int j = v >> 24;
      int row = (v >> 16) & 255, s0 = (v >> 8) & 255, E = (int)(v & 255);
      int w0 = s0 >> 6, w1 = E >> 6;
      for (int wi = w0; wi <= w1; wi++){
        int lo = max(s0, wi << 6), hi = min(E + 1, (wi << 6) + 64);
        u64 mask = (hi - lo == 64) ? ~0ull : ((((u64)1 << (hi - lo)) - 1) << (lo - (wi << 6)));
        int wofs = row * 4 + wi;
        for (int k2 = 0; k2 < n0; k2++){
          int c = __popcll(Pb[(size_t)k2 * 1024 + wofs] & mask);
          if (c) atomicAdd(&cnt[j*KCAP + k2], c);
        }
      }
    }
    __syncthreads();
    // per-j argmax (entries k>=n0 are exactly 0; strict > keeps earliest index)
    if (t < KCAP){
      float sn = scaleSel[(size_t)u*KCAP + t];
      int best = 0; float bv = 0.0f;
      if (sn > 0.0f && n0 > 0){
        bv = sn * spL[0] * (float)cnt[t*KCAP + 0];
        for (int k2 = 1; k2 < n0; k2++){
          float ov = sn * spL[k2] * (float)cnt[t*KCAP + k2];
          if (ov > bv){ bv = ov; best = k2; }
        }
      }
      bestA[t] = best; bvA[t] = bv;
    }
    __syncthreads();
    // sequential decisions (mirrors lax.scan)
    if (t == 0){
      int n = n0;
      for (int j = 0; j < KCAP; j++){
        add_dst[j] = -1;
        float sv = scaleSel[(size_t)u*KCAP + j];
        if (sv <= 0.0f) continue;                    // invalid comp: no-op
        if (bvA[j] > 0.0f){                          // matched: overwrite stored slot
          bar[bestA[j]*MAXI + tval] = sSel[(size_t)u*KCAP + j];
        } else if (n < KCAP){                        // add new component
          bar[n*MAXI + tval] = sSel[(size_t)u*KCAP + j];
          spL[n] = sv;
          add_dst[j] = n;
          n++;
        }
      }
      nS = n;
    }
    __syncthreads();
    // zero Pbm slots for added comps
    for (int j = 0; j < KCAP; j++){
      int d = add_dst[j];
      if (d < 0) continue;
      u64* dst = Pb + (size_t)d * 1024;
      for (int x = t; x < 1024; x += 1024) dst[x] = 0ull;
    }
    __syncthreads();
    // paint runs of added comps
    for (int i = t; i < NS; i += 1024){
      u32 v = rp[i];
      int j = v >> 24;
      int d = add_dst[j];
      if (d < 0) continue;
      int row = (v >> 16) & 255, s0 = (v >> 8) & 255, E = (int)(v & 255);
      int w0 = s0 >> 6, w1 = E >> 6;
      u64* dst = Pb + (size_t)d * 1024 + row * 4;
      for (int wi = w0; wi <= w1; wi++){
        int lo = max(s0, wi << 6), hi = min(E + 1, (wi << 6) + 64);
        u64 mask = (hi - lo == 64) ? ~0ull : ((((u64)1 << (hi - lo)) - 1) << (lo - (wi << 6)));
        atomicOr(&dst[wi], mask);
      }
    }
    __syncthreads();
  }
  if (t == 0) n24[w] = nS;
}

// ---------------- final loss ----------------
__global__ void k_loss(const float* __restrict__ barP, const float* __restrict__ barT,
                       const int* __restrict__ n24, float* __restrict__ out){
  if (blockIdx.x != 0 || threadIdx.x != 0) return;
  float total = 0.0f;
  for (int s = 0; s < BC; s++){
    int np = n24[s], nt = n24[12 + s];
    for (int k = 0; k < KCAP; k++){
      if (k >= np) continue;
      const float* bp = barP + (s*KCAP + k)*MAXI;
      float pmax = bp[0];
      for (int t = 1; t < MAXI; t++) pmax = fmaxf(pmax, bp[t]);
      if (!(pmax > 0.0f)) pmax = 1.0f;
      float acc = 0.0f;
      for (int t = 0; t < MAXI; t++){
        float tv = (k < nt) ? barT[(s*KCAP + k)*MAXI + t] : 0.0f;
        float d = tv - bp[t];
        acc += d * d;
      }
      total += acc / (pmax * pmax);
    }
  }
  out[0] = total * 0.25f;   // mean over B=4
}

extern "C" void kernel_launch(void* const* d_in, const int* in_sizes, int n_in,
                              void* d_out, int out_size, void* d_ws, size_t ws_size,
                              hipStream_t stream){
  const float* pred = (const float*)d_in[0];
  const float* gum  = (const float*)d_in[1];
  const int*   tgt  = (const int*)d_in[2];
  float* out = (float*)d_out;
  char* ws = (char*)d_ws;
  size_t off = 0;
  auto alloc = [&](size_t bytes)->char*{
    char* p = ws + off;
    off += (bytes + 255) & ~(size_t)255;
    return p;
  };
  u64* bmAll   = (u64*)alloc((size_t)NSLOT*1024*8);         // 0.98 MB
  u32* rootPk  = (u32*)alloc((size_t)NSLOT*RUNCAP*4);       // 7.9 MB (roots, then selRuns)
  int* selCnt  = (int*)alloc(NSLOT*4);
  float* sSel     = (float*)alloc((size_t)NSLOT*KCAP*4);
  float* scaleSel = (float*)alloc((size_t)NSLOT*KCAP*4);
  u64* Pbm     = (u64*)alloc((size_t)NCH*KCAP*1024*8);      // 6.3 MB
  int* n24     = (int*)alloc(NCH*4);
  // zero region: barP | barT
  size_t zbytes = (size_t)(BC*KCAP*MAXI*2)*4;
  char* zreg = alloc(zbytes);
  float* barP = (float*)zreg;
  float* barT = barP + BC*KCAP*MAXI;
  if (off > ws_size) return;

  hipMemsetAsync(zreg, 0, zbytes, stream);
  // binarize both passes' base masks (steps g=0 and g=5)
  k_bin<<<(NB*HW)/256,256,0,stream>>>(pred, gum, tgt, bmAll);
  // morphology: e1/d1 from base, then e2/d2, both passes batched
  k_morph4<<<192,256,0,stream>>>(bmAll, bmAll, make_int4(0,0,5,5), make_int4(1,3,6,8), make_int4(1,0,1,0));
  k_morph4<<<192,256,0,stream>>>(bmAll, bmAll, make_int4(1,3,6,8), make_int4(2,4,7,9), make_int4(1,0,1,0));
  // run-based CC + selection over all 120 slots
  k_cc_runs<<<NSLOT,256,0,stream>>>(bmAll, rootPk, selCnt, sSel, scaleSel);
  // full matching chain (5 steps internal), 24 independent blocks
  k_chainall<<<NCH,1024,0,stream>>>(rootPk, selCnt, sSel, scaleSel, barP, barT, n24, Pbm);
  k_loss<<<1,64,0,stream>>>(barP, barT, n24, out);
}

// Round 9
// 260.773 us; speedup vs baseline: 7.0046x; 1.5255x over previous
//
#include <hip/hip_runtime.h>

#define NB 4
#define NC 3
#define BC 12
#define HW 65536
#define KCAP 32
#define MAXI 5
#define RUNCAP 16384
#define NSLOT 120     // 10 steps x 12 (b,c) slots
#define NCH 24        // chain slots: 2 passes x 12
#define REGQ 8        // cached root entries per thread (8*1024 = 8192)
#define REGTOT (REGQ*1024)

typedef unsigned long long u64;
typedef unsigned int u32;

// ---------------- union-find (lock-free, link-to-MAX, path halving) ----------------
// root = MAX run index of the component -> root run holds the comp's max pixel.
__device__ __forceinline__ int uf_find(int* P, int x){
  while (true){
    int p = P[x];
    if (p == x) return x;
    int gp = P[p];
    if (gp == p) return p;
    P[x] = gp;   // path halving
    x = gp;
  }
}
__device__ __forceinline__ void uf_union_max(int* P, int a, int b){
  while (true){
    a = uf_find(P, a); b = uf_find(P, b);
    if (a == b) return;
    if (a > b){ int t = a; a = b; b = t; }   // a < b: link smaller root to larger
    int old = atomicCAS(&P[a], a, b);
    if (old == a) return;
    a = old;
  }
}

// walk runs of a 256-bit row (4 u64 words); emit(start, end_exclusive)
template<typename F>
__device__ __forceinline__ void walk_runs(const u64* wv, F&& emit){
  int open_s = -1;
  #pragma unroll
  for (int wi = 0; wi < 4; wi++){
    u64 v = wv[wi];
    int base = wi << 6;
    int pos = 0;
    while (pos < 64){
      u64 rem = v >> pos;
      if (open_s >= 0){
        u64 nz = ~rem;
        int z = nz ? __builtin_ctzll(nz) : 64;     // first zero at/after pos
        if (z >= 64 - pos){ pos = 64; }            // run continues past word
        else { emit(open_s, base + pos + z); open_s = -1; pos += z; }
      } else {
        if (rem == 0ull){ pos = 64; }
        else {
          int o = __builtin_ctzll(rem);            // first one
          open_s = base + pos + o;
          pos += o;
        }
      }
    }
  }
  if (open_s >= 0) emit(open_s, 256);
}

// ---------------- binarization: both base masks (pred -> g=0, tgt -> g=5) ----------------
__global__ void k_bin(const float* __restrict__ pred, const float* __restrict__ gum,
                      const int* __restrict__ tgt, u64* __restrict__ bmAll){
  int g = blockIdx.x * 256 + threadIdx.x;    // NB*HW threads
  int b = g >> 16, p = g & (HW - 1);
  size_t base = (size_t)b * NC * HW + p;
  float v0 = pred[base]        + gum[base];
  float v1 = pred[base + HW]   + gum[base + HW];
  float v2 = pred[base + 2*HW] + gum[base + 2*HW];
  int a = 0; float m = v0;
  if (v1 > m){ m = v1; a = 1; }
  if (v2 > m){ m = v2; a = 2; }
  int tg = tgt[(size_t)b * HW + p];
  u64 p0 = __ballot(a == 0), p1 = __ballot(a == 1), p2 = __ballot(a == 2);
  u64 t0 = __ballot(tg == 0), t1 = __ballot(tg == 1), t2 = __ballot(tg == 2);
  if ((threadIdx.x & 63) == 0){
    int w = p >> 6;
    int sp = b * NC;                       // pass0 base: step g=0
    bmAll[(size_t)(sp + 0) * 1024 + w] = p0;
    bmAll[(size_t)(sp + 1) * 1024 + w] = p1;
    bmAll[(size_t)(sp + 2) * 1024 + w] = p2;
    int st = 60 + b * NC;                  // pass1 base: step g=5
    bmAll[(size_t)(st + 0) * 1024 + w] = t0;
    bmAll[(size_t)(st + 1) * 1024 + w] = t1;
    bmAll[(size_t)(st + 2) * 1024 + w] = t2;
  }
}

// ---------------- 5x5 morphology on bitmaps: 4 independent jobs per launch ----------------
__global__ void k_morph4(const u64* __restrict__ bmAll, u64* __restrict__ bmAllW,
                         int4 srcs, int4 dsts, int4 flgs){
  int t = blockIdx.x * 256 + threadIdx.x;  // 4 * 12 * 1024 = 49152
  int job = t / 12288, rest = t % 12288;
  int s = rest >> 10, word = rest & 1023;
  int row = word >> 2, w = word & 3;
  int srcG = job == 0 ? srcs.x : job == 1 ? srcs.y : job == 2 ? srcs.z : srcs.w;
  int dstG = job == 0 ? dsts.x : job == 1 ? dsts.y : job == 2 ? dsts.z : dsts.w;
  int er   = job == 0 ? flgs.x : job == 1 ? flgs.y : job == 2 ? flgs.z : flgs.w;
  const u64* bs = bmAll + (size_t)(srcG * BC + s) * 1024;
  u64 res = er ? ~0ull : 0ull;
  for (int dy = -2; dy <= 2; dy++){
    int y = row + dy;
    if (y < 0 || y > 255){ if (er) res = 0; continue; }
    const u64* rw = bs + y * 4;
    u64 m = rw[w];
    u64 l = (w > 0) ? rw[w-1] : 0ull;
    u64 r = (w < 3) ? rw[w+1] : 0ull;
    u64 x1l = (m << 1) | (l >> 63);
    u64 x2l = (m << 2) | (l >> 62);
    u64 x1r = (m >> 1) | (r << 63);
    u64 x2r = (m >> 2) | (r << 62);
    u64 h = er ? (m & x1l & x2l & x1r & x2r) : (m | x1l | x2l | x1r | x2r);
    res = er ? (res & h) : (res | h);
  }
  bmAllW[(size_t)(dstG * BC + s) * 1024 + word] = res;
}

// ---------------- run-based CC in LDS, 1024 threads/block, one block/slot ----------------
// par: low 14 bits = parent/root idx, high bits accumulate comp size (at root only).
__global__ __launch_bounds__(1024) void k_cc_runs(
    const u64* __restrict__ bmAll, u32* __restrict__ rootPk /* -> selRuns */,
    int* __restrict__ selCnt, float* __restrict__ sSel, float* __restrict__ scaleSel){
  __shared__ int par[RUNCAP];      // 64 KB
  __shared__ u32 pkz[RUNCAP];      // 64 KB: pk, then root->j map
  __shared__ int rs[257];
  __shared__ u32 used[RUNCAP/32];  // 2 KB (fallback only)
  __shared__ int selRoot[KCAP];
  __shared__ u64 wred[16];
  __shared__ u64 bestS;
  __shared__ int nRootS, lmS, nSelS;
  int u = blockIdx.x, t = threadIdx.x;
  bool rowT = t < 256;             // thread t<256 owns row t
  u64 wv[4] = {0,0,0,0};
  int nr = 0;
  if (rowT){
    const u64* bp = bmAll + (size_t)u * 1024 + t * 4;
    #pragma unroll
    for (int i = 0; i < 4; i++) wv[i] = bp[i];
    walk_runs(wv, [&](int a, int b){ (void)a; (void)b; nr++; });
    rs[t] = nr;
  }
  if (t == 0){ nRootS = 0; lmS = 0; nSelS = 0; }
  if (t < KCAP) selRoot[t] = -1;
  for (int i = t; i < RUNCAP/32; i += 1024) used[i] = 0;
  __syncthreads();
  // inclusive Hillis-Steele scan of run counts (rows 0..255)
  for (int d = 1; d < 256; d <<= 1){
    int add = 0;
    if (rowT && t >= d) add = rs[t - d];
    __syncthreads();
    if (rowT) rs[t] += add;
    __syncthreads();
  }
  int incl = rowT ? rs[t] : 0;
  __syncthreads();
  if (rowT) rs[t] = incl - nr;       // exclusive offset (my base)
  if (t == 255) rs[256] = incl;      // total
  __syncthreads();
  int NR = rs[256];
  int NRc = NR < RUNCAP ? NR : RUNCAP;
  int myBase = rowT ? rs[t] : 0;
  size_t base = (size_t)u * RUNCAP;
  for (int i = t; i < NRc; i += 1024) par[i] = i;
  if (rowT){
    int o = myBase;
    walk_runs(wv, [&](int a, int b){
      if (o < RUNCAP) pkz[o] = ((u32)t << 16) | ((u32)a << 8) | (u32)(b - 1);
      o++;
    });
  }
  __syncthreads();
  // seam unions, one RUN per thread: binary search prev-row sorted run list.
  // overlap (8-conn) iff E1 >= s2-1 && s1 <= E2+1.
  for (int i = t; i < NRc; i += 1024){
    u32 v = pkz[i];
    int r = v >> 16;
    if (r == 0) continue;
    int s2 = (int)((v >> 8) & 255), E2 = (int)(v & 255);
    int a0 = rs[r-1], a1 = rs[r];
    if (a1 > NRc) a1 = NRc;
    if (a0 >= a1) continue;
    int lo = a0, hi = a1;
    while (lo < hi){
      int mid = (lo + hi) >> 1;
      if ((int)(pkz[mid] & 255) >= s2 - 1) hi = mid; else lo = mid + 1;
    }
    for (int j = lo; j < a1; j++){
      int s1 = (int)((pkz[j] >> 8) & 255);
      if (s1 > E2 + 1) break;
      uf_union_max(par, i, j);
    }
  }
  __syncthreads();
  // flatten (par low bits are pure parent indices here)
  for (int i = t; i < NRc; i += 1024){
    int r = i, p = par[r];
    while (p != r){ r = p; p = par[r]; }
    par[i] = r;
  }
  __syncthreads();
  // aggregate per run: size into par[root] high bits; compact roots; global max pixel
  {
    int lm = 0;
    for (int i = t; i < NRc; i += 1024){
      u32 v = pkz[i];
      int s0 = (int)((v >> 8) & 255), E = (int)(v & 255);
      int root = par[i] & 16383;
      atomicAdd(&par[root], (E - s0 + 1) << 14);
      int pix = (int)(v >> 16) * 256 + E;
      lm = max(lm, pix);
      if (root == i && pix > 0){           // root run holds comp's max pixel (= label)
        int pos = atomicAdd(&nRootS, 1);
        rootPk[base + pos] = ((u32)pix << 14) | (u32)i;   // pix:16b | runIdx:14b
      }
    }
    atomicMax(&lmS, lm);
  }
  __syncthreads();
  float maxLf = (float)(lmS >= 1 ? lmS : 1);
  int nRoots = nRootS;
  // register cache of packed keys: f32(size*lab)<<32 | (0xFFFF-lab)<<16 | id
  // labels unique per comp => total order, deterministic.
  u64 myKeys[REGQ];
  #pragma unroll
  for (int q = 0; q < REGQ; q++){
    myKeys[q] = 0;
    int e = q * 1024 + t;
    if (e < nRoots){
      u32 v = rootPk[base + e];
      int lab = (int)(v >> 14);
      int idx = (int)(v & 16383);
      float key = (float)(((u32)par[idx]) >> 14) * (float)lab;
      myKeys[q] = ((u64)__float_as_uint(key) << 32) | ((u64)(0xFFFFu - (u32)lab) << 16)
                | ((u64)q << 10) | (u64)t;         // id: q(3b)<<10 | tid(10b), bit15=0
    }
  }
  // 32 selection rounds: register scan + wave shfl + 16-wave LDS reduce
  for (int r = 0; r < KCAP; r++){
    u64 b = 0;
    #pragma unroll
    for (int q = 0; q < REGQ; q++) b = (myKeys[q] > b) ? myKeys[q] : b;
    if (nRoots > REGTOT){                           // rare fallback: tail from global
      for (int e = REGTOT + t; e < nRoots; e += 1024){
        if ((used[e >> 5] >> (e & 31)) & 1u) continue;
        u32 v = rootPk[base + e];
        int lab = (int)(v >> 14);
        int idx = (int)(v & 16383);
        float key = (float)(((u32)par[idx]) >> 14) * (float)lab;
        u64 cand = ((u64)__float_as_uint(key) << 32) | ((u64)(0xFFFFu - (u32)lab) << 16)
                 | 0x8000u | (u64)e;                // bit15=1, e:14b
        b = (cand > b) ? cand : b;
      }
    }
    #pragma unroll
    for (int off = 32; off > 0; off >>= 1){
      u64 o = __shfl_xor(b, off);
      b = (o > b) ? o : b;
    }
    if ((t & 63) == 0) wred[t >> 6] = b;
    __syncthreads();
    if (t == 0){
      u64 m = 0;
      #pragma unroll
      for (int wq = 0; wq < 16; wq++) m = (wred[wq] > m) ? wred[wq] : m;
      bestS = m;
    }
    __syncthreads();
    u64 bestAll = bestS;
    if (bestAll == 0){
      if (t == 0){
        for (int q = r; q < KCAP; q++){ sSel[u*KCAP + q] = 0.0f; scaleSel[u*KCAP + q] = 0.0f; }
      }
      break;
    }
    if (!(bestAll & 0x8000ull)){
      #pragma unroll
      for (int q = 0; q < REGQ; q++) if (myKeys[q] == bestAll) myKeys[q] = 0;
    }
    if (t == 0){
      int e;
      if (bestAll & 0x8000ull){
        e = (int)(bestAll & 0x3FFF);
        used[e >> 5] |= 1u << (e & 31);
      } else {
        e = (int)((bestAll >> 10) & 7) * 1024 + (int)(bestAll & 1023);
      }
      int lab = 0xFFFF - (int)((bestAll >> 16) & 0xFFFF);
      selRoot[r] = (int)(rootPk[base + e] & 16383);
      sSel[u*KCAP + r]     = __uint_as_float((u32)(bestAll >> 32)) / maxLf;
      scaleSel[u*KCAP + r] = (float)lab / maxLf;
    }
    __syncthreads();
  }
  __syncthreads();
  // pkz -> root->j map; emit compact selected runs into rootPk (selRuns)
  for (int i = t; i < NRc; i += 1024) pkz[i] = 255u;
  __syncthreads();
  if (t < KCAP && selRoot[t] >= 0) pkz[selRoot[t]] = (u32)t;
  __syncthreads();
  if (rowT){
    int o = myBase;
    walk_runs(wv, [&](int a, int b){
      if (o < RUNCAP){
        u32 j = pkz[par[o] & 16383];
        if (j < KCAP){
          int pos = atomicAdd(&nSelS, 1);
          rootPk[base + pos] = (j << 24) | ((u32)t << 16) | ((u32)a << 8) | (u32)(b - 1);
        }
      }
      o++;
    });
  }
  __syncthreads();
  if (t == 0) selCnt[u] = nSelS;
}

// ---------------- full matching chain: 5 steps in one kernel, one block per (pass,slot) ----
__global__ __launch_bounds__(1024) void k_chainall(
    const u32* __restrict__ selRuns, const int* __restrict__ selCnt,
    const float* __restrict__ sSel, const float* __restrict__ scaleSel,
    float* __restrict__ barP, float* __restrict__ barT,
    int* __restrict__ n24, u64* __restrict__ Pbm){
  int w = blockIdx.x, t = threadIdx.x;
  int pass = w / 12, s = w % 12;
  __shared__ int cnt[KCAP*KCAP];
  __shared__ float spL[KCAP];
  __shared__ int add_dst[KCAP];
  __shared__ int bestA[KCAP];
  __shared__ float bvA[KCAP];
  __shared__ int nS;
  if (t < KCAP) spL[t] = 0.0f;
  if (t == 0) nS = 0;
  float* bar = (pass ? barT : barP) + (size_t)s * KCAP * MAXI;
  u64* Pb = Pbm + (size_t)w * KCAP * 1024;
  #pragma unroll 1
  for (int st = 0; st < 5; st++){
    int u = (pass * 5 + st) * BC + s;
    int tval = (st < 3) ? st + 2 : (st == 3 ? 1 : 0);   // schedule {2,3,4,1,0}
    for (int i = t; i < KCAP*KCAP; i += 1024) cnt[i] = 0;
    __syncthreads();
    int n0 = nS;
    int NS = selCnt[u];
    const u32* rp = selRuns + (size_t)u * RUNCAP;
    // OV counts: per-run register accumulate over words, then one atomic per comp
    for (int i = t; i < NS; i += 1024){
      u32 v = rp[i];
      int j = v >> 24;
      int row = (v >> 16) & 255, s0 = (v >> 8) & 255, E = (int)(v & 255);
      int w0 = s0 >> 6, w1 = E >> 6;
      int acc[KCAP];
      #pragma unroll
      for (int k2 = 0; k2 < KCAP; k2++) acc[k2] = 0;
      for (int wi = w0; wi <= w1; wi++){
        int lo = max(s0, wi << 6), hi = min(E + 1, (wi << 6) + 64);
        u64 mask = (hi - lo == 64) ? ~0ull : ((((u64)1 << (hi - lo)) - 1) << (lo - (wi << 6)));
        int wofs = row * 4 + wi;
        #pragma unroll
        for (int k2 = 0; k2 < KCAP; k2++){
          if (k2 < n0) acc[k2] += __popcll(Pb[(size_t)k2 * 1024 + wofs] & mask);
        }
      }
      #pragma unroll
      for (int k2 = 0; k2 < KCAP; k2++){
        if (k2 < n0 && acc[k2]) atomicAdd(&cnt[j*KCAP + k2], acc[k2]);
      }
    }
    __syncthreads();
    // per-j argmax (entries k>=n0 are exactly 0; strict > keeps earliest index)
    if (t < KCAP){
      float sn = scaleSel[(size_t)u*KCAP + t];
      int best = 0; float bv = 0.0f;
      if (sn > 0.0f && n0 > 0){
        bv = sn * spL[0] * (float)cnt[t*KCAP + 0];
        for (int k2 = 1; k2 < n0; k2++){
          float ov = sn * spL[k2] * (float)cnt[t*KCAP + k2];
          if (ov > bv){ bv = ov; best = k2; }
        }
      }
      bestA[t] = best; bvA[t] = bv;
    }
    __syncthreads();
    // sequential decisions (mirrors lax.scan)
    if (t == 0){
      int n = n0;
      for (int j = 0; j < KCAP; j++){
        add_dst[j] = -1;
        float sv = scaleSel[(size_t)u*KCAP + j];
        if (sv <= 0.0f) continue;                    // invalid comp: no-op
        if (bvA[j] > 0.0f){                          // matched: overwrite stored slot
          bar[bestA[j]*MAXI + tval] = sSel[(size_t)u*KCAP + j];
        } else if (n < KCAP){                        // add new component
          bar[n*MAXI + tval] = sSel[(size_t)u*KCAP + j];
          spL[n] = sv;
          add_dst[j] = n;
          n++;
        }
      }
      nS = n;
    }
    __syncthreads();
    // zero Pbm slots for added comps
    for (int j = 0; j < KCAP; j++){
      int d = add_dst[j];
      if (d < 0) continue;
      u64* dst = Pb + (size_t)d * 1024;
      for (int x = t; x < 1024; x += 1024) dst[x] = 0ull;
    }
    __syncthreads();
    // paint runs of added comps
    for (int i = t; i < NS; i += 1024){
      u32 v = rp[i];
      int j = v >> 24;
      int d = add_dst[j];
      if (d < 0) continue;
      int row = (v >> 16) & 255, s0 = (v >> 8) & 255, E = (int)(v & 255);
      int w0 = s0 >> 6, w1 = E >> 6;
      u64* dst = Pb + (size_t)d * 1024 + row * 4;
      for (int wi = w0; wi <= w1; wi++){
        int lo = max(s0, wi << 6), hi = min(E + 1, (wi << 6) + 64);
        u64 mask = (hi - lo == 64) ? ~0ull : ((((u64)1 << (hi - lo)) - 1) << (lo - (wi << 6)));
        atomicOr(&dst[wi], mask);
      }
    }
    __syncthreads();
  }
  if (t == 0) n24[w] = nS;
}

// ---------------- final loss (parallel: one thread per (s,k), LDS reduce) ----------------
__global__ void k_loss(const float* __restrict__ barP, const float* __restrict__ barT,
                       const int* __restrict__ n24, float* __restrict__ out){
  __shared__ float red[512];
  int t = threadIdx.x;
  float val = 0.0f;
  if (t < BC * KCAP){
    int s = t >> 5, k = t & 31;
    int np = n24[s], nt = n24[12 + s];
    if (k < np){
      const float* bp = barP + (size_t)(s*KCAP + k)*MAXI;
      float pmax = bp[0];
      #pragma unroll
      for (int q = 1; q < MAXI; q++) pmax = fmaxf(pmax, bp[q]);
      if (!(pmax > 0.0f)) pmax = 1.0f;
      float acc = 0.0f;
      #pragma unroll
      for (int q = 0; q < MAXI; q++){
        float tv = (k < nt) ? barT[(size_t)(s*KCAP + k)*MAXI + q] : 0.0f;
        float d = tv - bp[q];
        acc += d * d;
      }
      val = acc / (pmax * pmax);
    }
  }
  red[t] = val;
  __syncthreads();
  for (int off = 256; off > 0; off >>= 1){
    if (t < off) red[t] += red[t + off];
    __syncthreads();
  }
  if (t == 0) out[0] = red[0] * 0.25f;   // mean over B=4
}

extern "C" void kernel_launch(void* const* d_in, const int* in_sizes, int n_in,
                              void* d_out, int out_size, void* d_ws, size_t ws_size,
                              hipStream_t stream){
  const float* pred = (const float*)d_in[0];
  const float* gum  = (const float*)d_in[1];
  const int*   tgt  = (const int*)d_in[2];
  float* out = (float*)d_out;
  char* ws = (char*)d_ws;
  size_t off = 0;
  auto alloc = [&](size_t bytes)->char*{
    char* p = ws + off;
    off += (bytes + 255) & ~(size_t)255;
    return p;
  };
  u64* bmAll   = (u64*)alloc((size_t)NSLOT*1024*8);         // 0.98 MB
  u32* rootPk  = (u32*)alloc((size_t)NSLOT*RUNCAP*4);       // 7.9 MB (roots, then selRuns)
  int* selCnt  = (int*)alloc(NSLOT*4);
  float* sSel     = (float*)alloc((size_t)NSLOT*KCAP*4);
  float* scaleSel = (float*)alloc((size_t)NSLOT*KCAP*4);
  u64* Pbm     = (u64*)alloc((size_t)NCH*KCAP*1024*8);      // 6.3 MB
  int* n24     = (int*)alloc(NCH*4);
  // zero region: barP | barT
  size_t zbytes = (size_t)(BC*KCAP*MAXI*2)*4;
  char* zreg = alloc(zbytes);
  float* barP = (float*)zreg;
  float* barT = barP + BC*KCAP*MAXI;
  if (off > ws_size) return;

  hipMemsetAsync(zreg, 0, zbytes, stream);
  // binarize both passes' base masks (steps g=0 and g=5)
  k_bin<<<(NB*HW)/256,256,0,stream>>>(pred, gum, tgt, bmAll);
  // morphology: e1/d1 from base, then e2/d2, both passes batched
  k_morph4<<<192,256,0,stream>>>(bmAll, bmAll, make_int4(0,0,5,5), make_int4(1,3,6,8), make_int4(1,0,1,0));
  k_morph4<<<192,256,0,stream>>>(bmAll, bmAll, make_int4(1,3,6,8), make_int4(2,4,7,9), make_int4(1,0,1,0));
  // run-based CC + selection over all 120 slots
  k_cc_runs<<<NSLOT,1024,0,stream>>>(bmAll, rootPk, selCnt, sSel, scaleSel);
  // full matching chain (5 steps internal), 24 independent blocks
  k_chainall<<<NCH,1024,0,stream>>>(rootPk, selCnt, sSel, scaleSel, barP, barT, n24, Pbm);
  k_loss<<<1,512,0,stream>>>(barP, barT, n24, out);
}